// Round 1
// baseline (153.124 us; speedup 1.0000x reference)
//
#include <hip/hip_runtime.h>
#include <hip/hip_bf16.h>

// Problem constants: B=64, N=32, S=256, D=128
#define B_SZ 64
#define N_Q 32
#define TOTAL_WG 1088   // 1024 in-batch + 64 neg-pair workgroups

typedef __attribute__((ext_vector_type(8))) short bf16x8;
typedef __attribute__((ext_vector_type(4))) float f32x4;

static __device__ __forceinline__ unsigned short f2bf(float f) {
    __hip_bfloat16 h = __float2bfloat16(f);
    return *reinterpret_cast<unsigned short*>(&h);
}

// Load 8 consecutive fp32 (32 B), convert to one bf16x8 fragment.
static __device__ __forceinline__ bf16x8 cvt_frag(const float* __restrict__ src) {
    float4 a = reinterpret_cast<const float4*>(src)[0];
    float4 b = reinterpret_cast<const float4*>(src)[1];
    union { bf16x8 v; unsigned short u[8]; } t;
    t.u[0] = f2bf(a.x); t.u[1] = f2bf(a.y); t.u[2] = f2bf(a.z); t.u[3] = f2bf(a.w);
    t.u[4] = f2bf(b.x); t.u[5] = f2bf(b.y); t.u[6] = f2bf(b.z); t.u[7] = f2bf(b.w);
    return t.v;
}

#define MFMA(A, Bv, C) __builtin_amdgcn_mfma_f32_16x16x32_bf16(A, Bv, C, 0, 0, 0)

// Direct global->LDS DMA (16 B/lane). Per-lane global address; wave-uniform LDS
// base; HW writes lane l at ldsbase + l*16 — exactly our linear docB layout.
static __device__ __forceinline__ void gload_lds16(const bf16x8* g, bf16x8* l) {
    __builtin_amdgcn_global_load_lds(
        (const __attribute__((address_space(1))) void*)g,
        (__attribute__((address_space(3))) void*)l,
        16, 0, 0);
}

static __device__ __forceinline__ float softplusf(float x) {
    return fmaxf(x, 0.0f) + log1pf(expf(-fabsf(x)));
}

// Direct fp32 -> bf16 convert + permute into MFMA fragment order. No LDS.
// DP (ushort8 idx o): o = doc*4096 + ch*1024 + kk*256 + nt*64 + ln
//    = doc[s = ch*64 + nt*16 + (ln&15)][k = kk*32 + (ln>>4)*8 .. +7]  (doc 64..127 = nd)
// QP (ushort8 idx g): g = b*512 + kk*128 + mt*64 + ln
//    = q[b][n = mt*16 + (ln&15)][k = kk*32 + (ln>>4)*8 .. +7]
__global__ __launch_bounds__(256) void cvt_permute(const float* __restrict__ q,
                                                   const float* __restrict__ dd,
                                                   const float* __restrict__ nd,
                                                   unsigned short* __restrict__ DP,
                                                   unsigned short* __restrict__ QP,
                                                   unsigned int* __restrict__ cnt) {
    const int blk = blockIdx.x, tid = threadIdx.x;
    if (blk == 0 && tid == 0) *cnt = 0u;   // ticket for maxsim's last-block loss
    if (blk < 2048) {
        const int o = blk * 256 + tid;           // 0..524287
        const int doc = o >> 12;
        const int u = o & 4095;
        const int ln = u & 63, nt = (u >> 6) & 3, kk = (u >> 8) & 3, ch = u >> 10;
        const int s  = ch * 64 + nt * 16 + (ln & 15);
        const int k0 = kk * 32 + (ln >> 4) * 8;
        const float* src = ((doc < 64) ? (dd + (size_t)doc * 32768)
                                       : (nd + (size_t)(doc - 64) * 32768)) + s * 128 + k0;
        reinterpret_cast<bf16x8*>(DP)[o] = cvt_frag(src);
    } else {
        const int g = (blk - 2048) * 256 + tid;  // 0..32767
        const int b = g >> 9, u = g & 511;
        const int ln = u & 63, mt = (u >> 6) & 1, kk = u >> 7;
        const int n  = mt * 16 + (ln & 15);
        const int k0 = kk * 32 + (ln >> 4) * 8;
        reinterpret_cast<bf16x8*>(QP)[g] = cvt_frag(q + (size_t)b * 4096 + n * 128 + k0);
    }
}

// Query-per-wave MaxSim, XCD-pinned doc columns.
// wg < 1024: x = wg&7 (XCD under default wg%8 placement), i = wg>>3;
//            column c = x*8 + (i&7)  -> all 16 wgs of column c land on XCD x,
//            so the 64 KiB doc tile stays in that XCD's L2 across its 16 stagers.
//            query b = (i>>3)*4 + wave.
// wg >= 1024: neg pair b = wg-1024 (doc slot 64+b); wave w handles s-chunk w only.
// Doc staged once in 64 KiB LDS via global_load_lds (no VGPR round-trip).
// Last block (device-scope ticket) computes the loss — no separate loss kernel.
__global__ __launch_bounds__(256, 2) void maxsim_kernel(const unsigned short* __restrict__ QP,
                                                        const unsigned short* __restrict__ DP,
                                                        float* __restrict__ scores,
                                                        unsigned int* __restrict__ cnt,
                                                        float* __restrict__ out) {
    const int wg  = blockIdx.x;
    const int tid = threadIdx.x;
    const int wave = tid >> 6, lane = tid & 63;
    const int l15 = lane & 15;

    __shared__ bf16x8 docB[4096];        // 64 KiB: [ch*1024 + kk*256 + nt*64 + lane]
    __shared__ float wredN[4][4][8];     // neg path: [wave][l4][mt*4+reg]
    __shared__ unsigned int lastBlk;

    const bf16x8* DP8 = reinterpret_cast<const bf16x8*>(DP);
    const bf16x8* QP8 = reinterpret_cast<const bf16x8*>(QP);

    int c, b;
    bool isNeg;
    if (wg < 1024) {
        const int x = wg & 7, i = wg >> 3;
        c = x * 8 + (i & 7);
        b = (i >> 3) * 4 + wave;
        isNeg = false;
    } else {
        b = wg - 1024; c = b; isNeg = true;
    }
    const int dcc = isNeg ? (64 + b) : c;

    // ---- stage this wave's doc quarter: 16 direct-to-LDS 1 KiB wave-loads ----
    const bf16x8* dsrc = DP8 + (size_t)dcc * 4096 + wave * 1024 + lane;
    #pragma unroll
    for (int f = 0; f < 16; ++f)
        gload_lds16(dsrc + f * 64, &docB[wave * 1024 + f * 64]);

    // ---- one batch: this wave's 8 A-fragments (A[kk][mt]) ----
    bf16x8 Af[4][2];
    const bf16x8* qsrc = QP8 + (size_t)b * 512 + lane;
    #pragma unroll
    for (int kk = 0; kk < 4; ++kk) {
        Af[kk][0] = qsrc[kk * 128];
        Af[kk][1] = qsrc[kk * 128 + 64];
    }
    __syncthreads();                     // drains the LDS-DMA (vmcnt) too

    // ---- compute: running per-lane row-max across s-chunks ----
    float rmax[2][4];
    #pragma unroll
    for (int mt = 0; mt < 2; ++mt)
        #pragma unroll
        for (int r = 0; r < 4; ++r) rmax[mt][r] = -3.0e38f;

    const int nch = isNeg ? 1 : 4;
    for (int i = 0; i < nch; ++i) {
        const int ch = isNeg ? wave : ((wave + i) & 3);
        f32x4 acc[2][4] = {};            // [mt][nt]
        #pragma unroll
        for (int kk = 0; kk < 4; ++kk) {
            #pragma unroll
            for (int nt = 0; nt < 4; ++nt) {
                bf16x8 Bv = docB[ch * 1024 + kk * 256 + nt * 64 + lane];
                acc[0][nt] = MFMA(Af[kk][0], Bv, acc[0][nt]);
                acc[1][nt] = MFMA(Af[kk][1], Bv, acc[1][nt]);
            }
        }
        #pragma unroll
        for (int mt = 0; mt < 2; ++mt)
            #pragma unroll
            for (int r = 0; r < 4; ++r)
                rmax[mt][r] = fmaxf(rmax[mt][r],
                    fmaxf(fmaxf(acc[mt][0][r], acc[mt][1][r]),
                          fmaxf(acc[mt][2][r], acc[mt][3][r])));
    }

    // ---- epilogue ----
    // Butterfly max over l15 (16 col-residues) -> row-max; then sum rows.
    float part = 0.0f;
    #pragma unroll
    for (int mt = 0; mt < 2; ++mt)
        #pragma unroll
        for (int r = 0; r < 4; ++r) {
            float m = rmax[mt][r];
            m = fmaxf(m, __shfl_xor(m, 1, 64));
            m = fmaxf(m, __shfl_xor(m, 2, 64));
            m = fmaxf(m, __shfl_xor(m, 4, 64));
            m = fmaxf(m, __shfl_xor(m, 8, 64));
            if (isNeg) {
                if (l15 == 0) wredN[wave][lane >> 4][mt * 4 + r] = m;
            } else {
                part += m;               // row n = mt*16 + (lane>>4)*4 + r
            }
        }
    if (!isNeg) {
        part += __shfl_xor(part, 16, 64);
        part += __shfl_xor(part, 32, 64);
        if (lane == 0) scores[(size_t)b * 65 + c] = part;
    } else {
        __syncthreads();                 // whole WG takes this branch (wg-uniform)
        if (tid < 32) {
            const int l4v = tid >> 3, slot = tid & 7;
            float m = fmaxf(fmaxf(wredN[0][l4v][slot], wredN[1][l4v][slot]),
                            fmaxf(wredN[2][l4v][slot], wredN[3][l4v][slot]));
            m += __shfl_xor(m, 1, 64);
            m += __shfl_xor(m, 2, 64);
            m += __shfl_xor(m, 4, 64);
            m += __shfl_xor(m, 8, 64);
            m += __shfl_xor(m, 16, 64);
            if (tid == 0) scores[(size_t)b * 65 + 64] = m;
        }
    }

    // ---- last-block loss (replaces loss_kernel launch) ----
    __threadfence();                     // release: score stores -> coherent point
    __syncthreads();
    if (tid == 0) lastBlk = (atomicAdd(cnt, 1u) == TOTAL_WG - 1u) ? 1u : 0u;
    __syncthreads();
    if (lastBlk != 0u) {
        __threadfence();                 // acquire: invalidate stale cache lines
        if (tid < 64) {
            const int bb = tid;          // one wave, lane = batch row
            const float* row = scores + bb * 65;
            const float pos  = row[bb];
            const float negq = row[64];
            float nib = -1e30f;
            #pragma unroll
            for (int cc = 0; cc < B_SZ; ++cc) {
                float v = row[cc] - ((cc == bb) ? 1000000.0f : 0.0f);
                nib = fmaxf(nib, v);
            }
            float t = softplusf(negq - pos) + softplusf(nib - pos);
            t += __shfl_xor(t, 1, 64);
            t += __shfl_xor(t, 2, 64);
            t += __shfl_xor(t, 4, 64);
            t += __shfl_xor(t, 8, 64);
            t += __shfl_xor(t, 16, 64);
            t += __shfl_xor(t, 32, 64);
            if (bb == 0) out[0] = t * (0.5f / 64.0f);
        }
    }
}

extern "C" void kernel_launch(void* const* d_in, const int* in_sizes, int n_in,
                              void* d_out, int out_size, void* d_ws, size_t ws_size,
                              hipStream_t stream) {
    const float* q  = (const float*)d_in[0];   // (64, 32, 128)
    const float* dd = (const float*)d_in[1];   // (64, 256, 128)
    const float* nd = (const float*)d_in[2];   // (64, 256, 128)
    float* out = (float*)d_out;

    // Workspace: DP (128 x 4096 ushort8 = 8 MiB) | QP (64 x 512 ushort8 = 512 KiB)
    //            | scores (64x65 f32) | cnt (u32)
    unsigned short* DP = (unsigned short*)d_ws;
    unsigned short* QP = DP + (size_t)128 * 32768;
    float* scores = (float*)(QP + (size_t)64 * 4096);
    unsigned int* cnt = (unsigned int*)(scores + 65 * 64);

    cvt_permute<<<2176, 256, 0, stream>>>(q, dd, nd, DP, QP, cnt);

    maxsim_kernel<<<TOTAL_WG, 256, 0, stream>>>(QP, DP, scores, cnt, out);
}

// Round 2
// 98.944 us; speedup vs baseline: 1.5476x; 1.5476x over previous
//
#include <hip/hip_runtime.h>
#include <hip/hip_bf16.h>

// Problem constants: B=64, N=32, S=256, D=128
#define B_SZ 64
#define N_Q 32

typedef __attribute__((ext_vector_type(8))) short bf16x8;
typedef __attribute__((ext_vector_type(4))) float f32x4;

static __device__ __forceinline__ unsigned short f2bf(float f) {
    __hip_bfloat16 h = __float2bfloat16(f);
    return *reinterpret_cast<unsigned short*>(&h);
}

// Load 8 consecutive fp32 (32 B), convert to one bf16x8 fragment.
static __device__ __forceinline__ bf16x8 cvt_frag(const float* __restrict__ src) {
    float4 a = reinterpret_cast<const float4*>(src)[0];
    float4 b = reinterpret_cast<const float4*>(src)[1];
    union { bf16x8 v; unsigned short u[8]; } t;
    t.u[0] = f2bf(a.x); t.u[1] = f2bf(a.y); t.u[2] = f2bf(a.z); t.u[3] = f2bf(a.w);
    t.u[4] = f2bf(b.x); t.u[5] = f2bf(b.y); t.u[6] = f2bf(b.z); t.u[7] = f2bf(b.w);
    return t.v;
}

#define MFMA(A, Bv, C) __builtin_amdgcn_mfma_f32_16x16x32_bf16(A, Bv, C, 0, 0, 0)

// Query-per-wave MaxSim with fused fp32->bf16 convert (no precompute pass).
// wg < 1024: x = wg&7 (XCD under default wg%8 placement), i = wg>>3;
//            column c = x*8 + (i&7)  -> all 16 wgs of column c land on XCD x,
//            so the doc tile stays in that XCD's L2 across its 16 stagers.
//            query b = (i>>3)*4 + wave.
// wg >= 1024: neg pair b = wg-1024 (doc = nd[b]); wave w handles s-chunk w only.
// Each wave converts+stages its doc quarter into 64 KiB LDS:
//   docB[ch*1024 + kk*256 + nt*64 + lane] = doc[s = ch*64+nt*16+(lane&15)]
//                                              [k = kk*32+(lane>>4)*8 .. +7]
// A-fragments (the wave's query) converted straight into 8 VGPR fragments.
// NO fences, NO device-scope sync — loss is a separate kernel.
__global__ __launch_bounds__(256, 2) void maxsim_kernel(const float* __restrict__ q,
                                                        const float* __restrict__ dd,
                                                        const float* __restrict__ nd,
                                                        float* __restrict__ scores) {
    const int wg  = blockIdx.x;
    const int tid = threadIdx.x;
    const int wave = tid >> 6, lane = tid & 63;
    const int l15 = lane & 15, lhi = lane >> 4;

    __shared__ bf16x8 docB[4096];        // 64 KiB: [ch*1024 + kk*256 + nt*64 + lane]
    __shared__ float wredN[4][4][8];     // neg path: [wave][l4][mt*4+reg]

    int c, b;
    bool isNeg;
    if (wg < 1024) {
        const int x = wg & 7, i = wg >> 3;
        c = x * 8 + (i & 7);
        b = (i >> 3) * 4 + wave;
        isNeg = false;
    } else {
        b = wg - 1024; c = b; isNeg = true;
    }

    // ---- stage + convert this wave's doc quarter (s-chunk ch = wave) ----
    const float* dsrc = (isNeg ? nd + (size_t)b * 32768
                               : dd + (size_t)c * 32768);
    #pragma unroll
    for (int kk = 0; kk < 4; ++kk)
        #pragma unroll
        for (int nt = 0; nt < 4; ++nt) {
            const int s  = wave * 64 + nt * 16 + l15;
            const int k0 = kk * 32 + lhi * 8;
            docB[wave * 1024 + kk * 256 + nt * 64 + lane] =
                cvt_frag(dsrc + (size_t)s * 128 + k0);
        }

    // ---- this wave's 8 A-fragments (A[kk][mt]) from fp32 q ----
    bf16x8 Af[4][2];
    #pragma unroll
    for (int kk = 0; kk < 4; ++kk)
        #pragma unroll
        for (int mt = 0; mt < 2; ++mt)
            Af[kk][mt] = cvt_frag(q + (size_t)b * 4096
                                    + (size_t)(mt * 16 + l15) * 128
                                    + kk * 32 + lhi * 8);
    __syncthreads();

    // ---- compute: running per-lane row-max across s-chunks ----
    float rmax[2][4];
    #pragma unroll
    for (int mt = 0; mt < 2; ++mt)
        #pragma unroll
        for (int r = 0; r < 4; ++r) rmax[mt][r] = -3.0e38f;

    const int nch = isNeg ? 1 : 4;
    for (int i = 0; i < nch; ++i) {
        const int ch = isNeg ? wave : ((wave + i) & 3);
        f32x4 acc[2][4] = {};            // [mt][nt]
        #pragma unroll
        for (int kk = 0; kk < 4; ++kk) {
            #pragma unroll
            for (int nt = 0; nt < 4; ++nt) {
                bf16x8 Bv = docB[ch * 1024 + kk * 256 + nt * 64 + lane];
                acc[0][nt] = MFMA(Af[kk][0], Bv, acc[0][nt]);
                acc[1][nt] = MFMA(Af[kk][1], Bv, acc[1][nt]);
            }
        }
        #pragma unroll
        for (int mt = 0; mt < 2; ++mt)
            #pragma unroll
            for (int r = 0; r < 4; ++r)
                rmax[mt][r] = fmaxf(rmax[mt][r],
                    fmaxf(fmaxf(acc[mt][0][r], acc[mt][1][r]),
                          fmaxf(acc[mt][2][r], acc[mt][3][r])));
    }

    // ---- epilogue ----
    // Butterfly max over l15 (16 col-residues) -> row-max; then sum rows.
    float part = 0.0f;
    #pragma unroll
    for (int mt = 0; mt < 2; ++mt)
        #pragma unroll
        for (int r = 0; r < 4; ++r) {
            float m = rmax[mt][r];
            m = fmaxf(m, __shfl_xor(m, 1, 64));
            m = fmaxf(m, __shfl_xor(m, 2, 64));
            m = fmaxf(m, __shfl_xor(m, 4, 64));
            m = fmaxf(m, __shfl_xor(m, 8, 64));
            if (isNeg) {
                if (l15 == 0) wredN[wave][lane >> 4][mt * 4 + r] = m;
            } else {
                part += m;               // row n = mt*16 + (lane>>4)*4 + r
            }
        }
    if (!isNeg) {
        part += __shfl_xor(part, 16, 64);
        part += __shfl_xor(part, 32, 64);
        if (lane == 0) scores[(size_t)b * 65 + c] = part;
    } else {
        __syncthreads();                 // whole WG takes this branch (wg-uniform)
        if (tid < 32) {
            const int l4v = tid >> 3, slot = tid & 7;
            float m = fmaxf(fmaxf(wredN[0][l4v][slot], wredN[1][l4v][slot]),
                            fmaxf(wredN[2][l4v][slot], wredN[3][l4v][slot]));
            m += __shfl_xor(m, 1, 64);
            m += __shfl_xor(m, 2, 64);
            m += __shfl_xor(m, 4, 64);
            m += __shfl_xor(m, 8, 64);
            m += __shfl_xor(m, 16, 64);
            if (tid == 0) scores[(size_t)b * 65 + 64] = m;
        }
    }
}

static __device__ __forceinline__ float softplusf(float x) {
    return fmaxf(x, 0.0f) + log1pf(expf(-fabsf(x)));
}

__global__ __launch_bounds__(64) void loss_kernel(const float* __restrict__ scores,
                                                  float* __restrict__ out) {
    const int b = threadIdx.x;           // 64 threads = 1 wave
    const float* row = scores + b * 65;
    const float pos  = row[b];
    const float negq = row[64];
    float nib = -1e30f;
    #pragma unroll
    for (int c = 0; c < B_SZ; ++c) {
        float v = row[c] - ((c == b) ? 1000000.0f : 0.0f);
        nib = fmaxf(nib, v);
    }
    float t = softplusf(negq - pos) + softplusf(nib - pos);
    t += __shfl_xor(t, 1, 64);
    t += __shfl_xor(t, 2, 64);
    t += __shfl_xor(t, 4, 64);
    t += __shfl_xor(t, 8, 64);
    t += __shfl_xor(t, 16, 64);
    t += __shfl_xor(t, 32, 64);
    if (b == 0) out[0] = t * (0.5f / 64.0f);
}

extern "C" void kernel_launch(void* const* d_in, const int* in_sizes, int n_in,
                              void* d_out, int out_size, void* d_ws, size_t ws_size,
                              hipStream_t stream) {
    const float* q  = (const float*)d_in[0];   // (64, 32, 128)
    const float* dd = (const float*)d_in[1];   // (64, 256, 128)
    const float* nd = (const float*)d_in[2];   // (64, 256, 128)
    float* out = (float*)d_out;

    // Workspace: scores (64 x 65 f32) only.
    float* scores = (float*)d_ws;

    maxsim_kernel<<<1024 + B_SZ, 256, 0, stream>>>(q, dd, nd, scores);
    loss_kernel<<<1, 64, 0, stream>>>(scores, out);
}

// Round 3
// 92.585 us; speedup vs baseline: 1.6539x; 1.0687x over previous
//
#include <hip/hip_runtime.h>
#include <hip/hip_bf16.h>

// Problem constants: B=64, N=32, S=256, D=128
#define B_SZ 64

typedef __attribute__((ext_vector_type(8))) short bf16x8;
typedef __attribute__((ext_vector_type(4))) float f32x4;

static __device__ __forceinline__ unsigned short f2bf(float f) {
    __hip_bfloat16 h = __float2bfloat16(f);
    return *reinterpret_cast<unsigned short*>(&h);
}

// Load 8 consecutive fp32 (32 B), convert to one bf16x8 fragment.
static __device__ __forceinline__ bf16x8 cvt_frag(const float* __restrict__ src) {
    float4 a = reinterpret_cast<const float4*>(src)[0];
    float4 b = reinterpret_cast<const float4*>(src)[1];
    union { bf16x8 v; unsigned short u[8]; } t;
    t.u[0] = f2bf(a.x); t.u[1] = f2bf(a.y); t.u[2] = f2bf(a.z); t.u[3] = f2bf(a.w);
    t.u[4] = f2bf(b.x); t.u[5] = f2bf(b.y); t.u[6] = f2bf(b.z); t.u[7] = f2bf(b.w);
    return t.v;
}

#define MFMA(A, Bv, C) __builtin_amdgcn_mfma_f32_16x16x32_bf16(A, Bv, C, 0, 0, 0)

// fp32 -> bf16 convert + permute into MFMA fragment order.
// DP (ushort8 idx): doc*4096 + ch*1024 + kk*256 + nt*64 + lane
//    = doc[s = ch*64 + nt*16 + (lane&15)][k = kk*32 + (lane>>4)*8 .. +7]
//    (doc 64..127 = nd). DP path: READS coalesced (each thread = 8 consecutive
//    floats of one row), writes 16B-scattered (absorbed by L2 write-back).
// QP (ushort8 idx g): g = b*512 + kk*128 + mt*64 + ln (writes coalesced).
__global__ __launch_bounds__(256) void cvt_permute(const float* __restrict__ q,
                                                   const float* __restrict__ dd,
                                                   const float* __restrict__ nd,
                                                   unsigned short* __restrict__ DP,
                                                   unsigned short* __restrict__ QP) {
    const int blk = blockIdx.x, tid = threadIdx.x;
    if (blk < 2048) {
        const int o = blk * 256 + tid;           // 0..524287 = (doc, s, k8)
        const int doc = o >> 12, rem = o & 4095; // rem = s*16 + k8
        const float* src = ((doc < 64) ? (dd + (size_t)doc * 32768)
                                       : (nd + (size_t)(doc - 64) * 32768)) + rem * 8;
        bf16x8 v = cvt_frag(src);
        const int s = rem >> 4, k8 = rem & 15;
        const int lane = (k8 & 3) * 16 + (s & 15);          // lhi*16 + l15
        const int idx = doc * 4096 + (s >> 6) * 1024        // ch
                      + (k8 >> 2) * 256                     // kk
                      + ((s >> 4) & 3) * 64 + lane;         // nt, lane
        reinterpret_cast<bf16x8*>(DP)[idx] = v;
    } else {
        const int g = (blk - 2048) * 256 + tid;  // 0..32767
        const int b = g >> 9, u = g & 511;
        const int ln = u & 63, mt = (u >> 6) & 1, kk = u >> 7;
        const int n  = mt * 16 + (ln & 15);
        const int k0 = kk * 32 + (ln >> 4) * 8;
        reinterpret_cast<bf16x8*>(QP)[g] = cvt_frag(q + (size_t)b * 4096 + n * 128 + k0);
    }
}

// B-in-register MaxSim.
// wg < 512 (pos): x = wg&7 (XCD), i = wg>>3; column c = x*8 + (i&7) -> all 8
//   blocks of column c land on XCD x. Block covers b in [ (i>>3)*8, +8 ).
// wg >= 512 (neg): pair b = wg-512, doc slot 64+b, single-b loop.
// Wave w holds s-chunk w's 16 B-fragments in 64 VGPRs (staged ONCE, dense
// 1 KiB loads); inner loop over b reuses them: 8 A-frag loads + 32 MFMAs per b.
// No LDS doc tile; cross-chunk max via 4 KiB wred at the end.
__global__ __launch_bounds__(256, 2) void maxsim_kernel(const unsigned short* __restrict__ QP,
                                                        const unsigned short* __restrict__ DP,
                                                        float* __restrict__ scores) {
    const int wg  = blockIdx.x;
    const int tid = threadIdx.x;
    const int wave = tid >> 6, lane = tid & 63;
    const int l15 = lane & 15;

    __shared__ float wred[8][4][4][8];   // [bi][wave][lhi][mt*4+r]

    const bf16x8* DP8 = reinterpret_cast<const bf16x8*>(DP);
    const bf16x8* QP8 = reinterpret_cast<const bf16x8*>(QP);

    int c, b0, nb, dcc;
    if (wg < 512) {
        const int x = wg & 7, i = wg >> 3;
        c   = x * 8 + (i & 7);
        b0  = (i >> 3) * 8;
        nb  = 8;
        dcc = c;
    } else {
        b0 = wg - 512; c = 64; nb = 1; dcc = 64 + b0;
    }

    // ---- stage this wave's s-chunk (ch = wave) into registers: 16 dense loads ----
    bf16x8 Bv[4][4];                     // [kk][nt]
    const bf16x8* dsrc = DP8 + (size_t)dcc * 4096 + wave * 1024 + lane;
    #pragma unroll
    for (int kk = 0; kk < 4; ++kk)
        #pragma unroll
        for (int nt = 0; nt < 4; ++nt)
            Bv[kk][nt] = dsrc[kk * 256 + nt * 64];

    // ---- loop over batches: A-frags from QP (dense), 32 MFMAs, fold, stash ----
    #pragma unroll 2
    for (int bi = 0; bi < nb; ++bi) {
        const int b = b0 + bi;
        bf16x8 Af[4][2];
        const bf16x8* qsrc = QP8 + (size_t)b * 512 + lane;
        #pragma unroll
        for (int kk = 0; kk < 4; ++kk) {
            Af[kk][0] = qsrc[kk * 128];
            Af[kk][1] = qsrc[kk * 128 + 64];
        }
        f32x4 acc[2][4] = {};            // [mt][nt]
        #pragma unroll
        for (int kk = 0; kk < 4; ++kk)
            #pragma unroll
            for (int nt = 0; nt < 4; ++nt) {
                acc[0][nt] = MFMA(Af[kk][0], Bv[kk][nt], acc[0][nt]);
                acc[1][nt] = MFMA(Af[kk][1], Bv[kk][nt], acc[1][nt]);
            }
        // max over this wave's 64 docs; butterfly over l15 -> per-row chunk max
        #pragma unroll
        for (int mt = 0; mt < 2; ++mt)
            #pragma unroll
            for (int r = 0; r < 4; ++r) {
                float m = fmaxf(fmaxf(acc[mt][0][r], acc[mt][1][r]),
                                fmaxf(acc[mt][2][r], acc[mt][3][r]));
                m = fmaxf(m, __shfl_xor(m, 1, 64));
                m = fmaxf(m, __shfl_xor(m, 2, 64));
                m = fmaxf(m, __shfl_xor(m, 4, 64));
                m = fmaxf(m, __shfl_xor(m, 8, 64));
                if (l15 == 0) wred[bi][wave][lane >> 4][mt * 4 + r] = m;
                // row n = mt*16 + (lane>>4)*4 + r
            }
    }
    __syncthreads();

    // ---- final: max over the 4 s-chunks, then sum over the 32 query rows ----
    if (tid < nb * 32) {
        const int bi = tid >> 5, n = tid & 31;
        const int slot = (n >> 4) * 4 + (n & 3);   // mt*4 + r
        const int lhi  = (n >> 2) & 3;
        float m = fmaxf(fmaxf(wred[bi][0][lhi][slot], wred[bi][1][lhi][slot]),
                        fmaxf(wred[bi][2][lhi][slot], wred[bi][3][lhi][slot]));
        m += __shfl_xor(m, 1, 32);
        m += __shfl_xor(m, 2, 32);
        m += __shfl_xor(m, 4, 32);
        m += __shfl_xor(m, 8, 32);
        m += __shfl_xor(m, 16, 32);
        if (n == 0) scores[(size_t)(b0 + bi) * 65 + c] = m;  // c==64 -> neg slot
    }
}

static __device__ __forceinline__ float softplusf(float x) {
    return fmaxf(x, 0.0f) + log1pf(expf(-fabsf(x)));
}

__global__ __launch_bounds__(64) void loss_kernel(const float* __restrict__ scores,
                                                  float* __restrict__ out) {
    const int b = threadIdx.x;           // 64 threads = 1 wave
    const float* row = scores + b * 65;
    const float pos  = row[b];
    const float negq = row[64];
    float nib = -1e30f;
    #pragma unroll
    for (int c = 0; c < B_SZ; ++c) {
        float v = row[c] - ((c == b) ? 1000000.0f : 0.0f);
        nib = fmaxf(nib, v);
    }
    float t = softplusf(negq - pos) + softplusf(nib - pos);
    t += __shfl_xor(t, 1, 64);
    t += __shfl_xor(t, 2, 64);
    t += __shfl_xor(t, 4, 64);
    t += __shfl_xor(t, 8, 64);
    t += __shfl_xor(t, 16, 64);
    t += __shfl_xor(t, 32, 64);
    if (b == 0) out[0] = t * (0.5f / 64.0f);
}

extern "C" void kernel_launch(void* const* d_in, const int* in_sizes, int n_in,
                              void* d_out, int out_size, void* d_ws, size_t ws_size,
                              hipStream_t stream) {
    const float* q  = (const float*)d_in[0];   // (64, 32, 128)
    const float* dd = (const float*)d_in[1];   // (64, 256, 128)
    const float* nd = (const float*)d_in[2];   // (64, 256, 128)
    float* out = (float*)d_out;

    // Workspace: DP (128 x 4096 ushort8 = 8 MiB) | QP (64 x 512 ushort8 = 512 KiB)
    //            | scores (64 x 65 f32)
    unsigned short* DP = (unsigned short*)d_ws;
    unsigned short* QP = DP + (size_t)128 * 32768;
    float* scores = (float*)(QP + (size_t)64 * 4096);

    cvt_permute<<<2176, 256, 0, stream>>>(q, dd, nd, DP, QP);
    maxsim_kernel<<<512 + B_SZ, 256, 0, stream>>>(QP, DP, scores);
    loss_kernel<<<1, 64, 0, stream>>>(scores, out);
}